// Round 8
// baseline (1264.515 us; speedup 1.0000x reference)
//
#include <hip/hip_runtime.h>
#include <hip/hip_bf16.h>

#define SEQ   20
#define PRED  30
#define TSTEPS (SEQ + PRED)
#define PEDS  16384
#define EMB   64
#define RNN   128
#define KTOT  192
#define PB    64
#define NT    512

typedef _Float16 half8 __attribute__((ext_vector_type(8)));
typedef __attribute__((ext_vector_type(4))) float f32x4;

__device__ __forceinline__ float sigm(float x) {
    return 1.f / (1.f + __expf(-x));
}
__device__ __forceinline__ float tanhfast(float x) {
    x = fmaxf(x, -15.f);
    float e = __expf(-2.f * x);
    return (1.f - e) / (1.f + e);
}

// B fragments (f16) pre-permuted: idx = ((kt*32 + nt)*64 + l)*8 + i ; nt = g*8 + jt
// row n = g*128 + jt*16 + (l&15) ; k = kt*32 + (l>>4)*8 + i
// W_cat[n][k]: k<64 -> W_ih[n][k], else W_hh[n][k-64].
// ewp[ke][4] = {Wemb[ke][0], Wemb[ke][1], bemb[ke], 0}
__global__ void prep_kernel(const float* __restrict__ Wih, const float* __restrict__ Whh,
                            const float* __restrict__ Wemb, const float* __restrict__ bemb,
                            _Float16* __restrict__ Bp, float* __restrict__ ewp) {
    int t = blockIdx.x * blockDim.x + threadIdx.x;
    if (t < 64) {
        ewp[t * 4 + 0] = Wemb[t * 2 + 0];
        ewp[t * 4 + 1] = Wemb[t * 2 + 1];
        ewp[t * 4 + 2] = bemb[t];
        ewp[t * 4 + 3] = 0.f;
    }
    if (t >= 6 * 32 * 64 * 8) return;
    int i  = t & 7;
    int l  = (t >> 3) & 63;
    int nt = (t >> 9) & 31;
    int kt = t >> 14;
    int n = (nt >> 3) * RNN + (nt & 7) * 16 + (l & 15);
    int k = kt * 32 + ((l >> 4) << 3) + i;
    float val = (k < EMB) ? Wih[n * EMB + k] : Whh[n * RNN + (k - EMB)];
    Bp[t] = (_Float16)val;
}

// LDS ~58.5 KB -> 2 blocks/CU (16 waves/CU). 4 waves/EU -> 128 VGPR cap.
__global__ __launch_bounds__(NT, 4) void lstm_kernel(
    const float* __restrict__ obs,
    const float* __restrict__ ewp,
    const float* __restrict__ bih,  const float* __restrict__ bhh,
    const _Float16* __restrict__ Bp,
    const float* __restrict__ Wout, const float* __restrict__ bout,
    float* __restrict__ out)
{
    // A = [e(64) ; h(128)] single-plane f16, row-major [64 ped][192 k] (384 B rows),
    // XOR-swizzled. B staged per half-kt (16 KB) double-buffered, per-wave-private.
    __shared__ __align__(16) char smA[64 * 384];    // 24 KB
    __shared__ __align__(16) char smB[2 * 16384];   // 32 KB B dbuf (half-kt slices)
    __shared__ float part[64 * 2 * 4];
    __shared__ float outs[64 * 2];

    const int tid = threadIdx.x;
    const int l   = tid & 63;
    const int w   = __builtin_amdgcn_readfirstlane(tid >> 6);  // wave 0..7
    const int pg  = blockIdx.x * PB + l;

    // zero A (h region must be 0 at step 0)
    for (int r = tid; r < (64 * 384) / 4; r += NT) ((int*)smA)[r] = 0;

    const int jlane = w * 16 + (l & 15);  // this lane's j column
    const int lrow  = (l >> 4) << 2;      // C/D row base
    const int kgrp  = (l >> 4) << 3;      // A/B k-group base

    float bias[4];
#pragma unroll
    for (int g = 0; g < 4; ++g) {
        int n = g * RNN + jlane;
        bias[g] = bih[n] + bhh[n];
    }

    float c[16];
#pragma unroll
    for (int q = 0; q < 16; ++q) c[q] = 0.f;

    // stage phase ph (= kt*2 + hh): wave w loads its 2 fragments (nt = hh*16 + q*8 + w),
    // 1 KB each; LDS dst = uniform base + lane*16 (linear).
    auto stage = [&](int ph, int buf) {
        const int kt = ph >> 1, hh = ph & 1;
#pragma unroll
        for (int q = 0; q < 2; ++q) {
            int nt   = hh * 16 + q * 8 + w;
            int slot = q * 8 + w;
            const _Float16* src = Bp + (((size_t)kt * 32 + nt) * 64 + l) * 8;
            __builtin_amdgcn_global_load_lds(
                (const __attribute__((address_space(1))) void*)src,
                (__attribute__((address_space(3))) void*)(smB + buf * 16384 + slot * 1024),
                16, 0, 0);
        }
    };

    stage(0, 0);  // prologue: phase0 -> buf0
    __syncthreads();

    for (int step = 0; step < TSTEPS; ++step) {
        // ---- E: e = relu(x @ Wemb.T + bemb) -> A rows k=0..63 (f16)
        float x0, x1;
        if (step < SEQ) {
            const float* xp = obs + ((size_t)step * PEDS + pg) * 2;
            x0 = xp[0]; x1 = xp[1];
        } else {
            x0 = outs[l * 2 + 0];
            x1 = outs[l * 2 + 1];
        }
        {
            half8 vh;
#pragma unroll
            for (int q = 0; q < 8; ++q) {
                const f32x4 ew = *(const f32x4*)(ewp + (w * 8 + q) * 4);
                float v = fmaf(x0, ew[0], fmaf(x1, ew[1], ew[2]));
                v = v > 0.f ? v : 0.f;
                vh[q] = (_Float16)v;
            }
            int off = (l * 384 + w * 16) ^ ((l & 7) << 4);
            *(half8*)(smA + off) = vh;
        }
        __syncthreads();  // B1: e (this step) + h (prev step) visible

        // ---- G: gates = A[64x192] @ B[192x512] + bias ; f16 1-pass, 12 phases
        f32x4 acc[4][4];  // [mt][gate]
#pragma unroll
        for (int mt = 0; mt < 4; ++mt)
#pragma unroll
            for (int g = 0; g < 4; ++g) {
                acc[mt][g][0] = bias[g]; acc[mt][g][1] = bias[g];
                acc[mt][g][2] = bias[g]; acc[mt][g][3] = bias[g];
            }
        half8 ah[4];
#pragma unroll
        for (int p = 0; p < 12; ++p) {
            const int kt = p >> 1, hh = p & 1, buf = p & 1;
            const int pn = (p < 11) ? p + 1 : 0;  // p=11 prefetches next step's phase0
            stage(pn, buf ^ 1);
            // this phase's 2 loads are oldest outstanding; allow the 2 just issued
            asm volatile("s_waitcnt vmcnt(2)" ::: "memory");
            half8 bf0 = *((const half8*)(smB + buf * 16384 + (0 * 8 + w) * 1024) + l);
            half8 bf1 = *((const half8*)(smB + buf * 16384 + (1 * 8 + w) * 1024) + l);
            if (hh == 0) {
#pragma unroll
                for (int mt = 0; mt < 4; ++mt) {
                    int ped = mt * 16 + (l & 15);
                    int off = (ped * 384 + (kt * 32 + kgrp) * 2) ^ ((ped & 7) << 4);
                    ah[mt] = *(const half8*)(smA + off);
                }
            }
            const int g0 = hh * 2;
#pragma unroll
            for (int mt = 0; mt < 4; ++mt) {
                acc[mt][g0 + 0] = __builtin_amdgcn_mfma_f32_16x16x32_f16(ah[mt], bf0, acc[mt][g0 + 0], 0, 0, 0);
                acc[mt][g0 + 1] = __builtin_amdgcn_mfma_f32_16x16x32_f16(ah[mt], bf1, acc[mt][g0 + 1], 0, 0, 0);
            }
        }
        __syncthreads();  // B2: all A reads done before h overwrite

        // ---- S: nonlinearities + c/h update; lane owns (ped = mt*16+lrow+r, j = jlane)
#pragma unroll
        for (int mt = 0; mt < 4; ++mt) {
#pragma unroll
            for (int r = 0; r < 4; ++r) {
                float gi = acc[mt][0][r], gf = acc[mt][1][r];
                float gg = acc[mt][2][r], go = acc[mt][3][r];
                float i_ = sigm(gi), f_ = sigm(gf), g_ = tanhfast(gg), o_ = sigm(go);
                float cn = fmaf(f_, c[mt * 4 + r], i_ * g_);
                c[mt * 4 + r] = cn;
                float hn = o_ * tanhfast(cn);
                int ped = mt * 16 + lrow + r;
                int offb = (ped * 384 + 128 + jlane * 2) ^ ((ped & 7) << 4);
                *(_Float16*)(smA + offb) = (_Float16)hn;
            }
        }

        // ---- O: out = h @ Wout.T + bout (h f16 from LDS)
        if (step >= SEQ - 1) {
            __syncthreads();  // B3: h(step) visible
            const int oo = w & 1, jq = w >> 1;
            float s = 0.f;
#pragma unroll
            for (int t = 0; t < 4; ++t) {
                int j = jq * 32 + t * 8;
                int off = (l * 384 + 128 + j * 2) ^ ((l & 7) << 4);
                half8 hh8 = *(const half8*)(smA + off);
                const f32x4 w0 = *(const f32x4*)(Wout + oo * RNN + j);
                const f32x4 w1 = *(const f32x4*)(Wout + oo * RNN + j + 4);
#pragma unroll
                for (int i = 0; i < 4; ++i) {
                    s = fmaf((float)hh8[i], w0[i], s);
                    s = fmaf((float)hh8[i + 4], w1[i], s);
                }
            }
            part[(l * 2 + oo) * 4 + jq] = s;
            __syncthreads();  // B4
            if (tid < 128) {
                int pp = tid & 63, o2 = tid >> 6;
                const float* pr = &part[(pp * 2 + o2) * 4];
                float o = bout[o2] + ((pr[0] + pr[1]) + (pr[2] + pr[3]));
                outs[pp * 2 + o2] = o;
                if (step >= SEQ)
                    out[((size_t)(step - SEQ) * PEDS + (blockIdx.x * PB + pp)) * 2 + o2] = o;
            }
            __syncthreads();  // B5: outs visible for next E
        }
    }
}

extern "C" void kernel_launch(void* const* d_in, const int* in_sizes, int n_in,
                              void* d_out, int out_size, void* d_ws, size_t ws_size,
                              hipStream_t stream) {
    const float* obs  = (const float*)d_in[0];
    const float* Wemb = (const float*)d_in[1];
    const float* bemb = (const float*)d_in[2];
    const float* Wih  = (const float*)d_in[3];
    const float* bih  = (const float*)d_in[4];
    const float* Whh  = (const float*)d_in[5];
    const float* bhh  = (const float*)d_in[6];
    const float* Wout = (const float*)d_in[7];
    const float* bout = (const float*)d_in[8];

    _Float16* Bp  = (_Float16*)d_ws;                 // 98304 f16 = 192 KB
    float*    ewp = (float*)(Bp + 6 * 32 * 64 * 8);  // 64*4 f32 = 1 KB

    prep_kernel<<<(6 * 32 * 64 * 8 + 255) / 256, 256, 0, stream>>>(Wih, Whh, Wemb, bemb, Bp, ewp);
    lstm_kernel<<<PEDS / PB, NT, 0, stream>>>(obs, ewp, bih, bhh, Bp, Wout, bout, (float*)d_out);
}

// Round 9
// 364.923 us; speedup vs baseline: 3.4652x; 3.4652x over previous
//
#include <hip/hip_runtime.h>
#include <hip/hip_bf16.h>

#define SEQ   20
#define PRED  30
#define TSTEPS (SEQ + PRED)
#define PEDS  16384
#define EMB   64
#define RNN   128
#define KTOT  192
#define PB    64
#define NT    512

typedef _Float16 half8 __attribute__((ext_vector_type(8)));
typedef __attribute__((ext_vector_type(4))) float f32x4;

__device__ __forceinline__ float sigm(float x) {
    return 1.f / (1.f + __expf(-x));
}
__device__ __forceinline__ float tanhfast(float x) {
    x = fmaxf(x, -15.f);
    float e = __expf(-2.f * x);
    return (1.f - e) / (1.f + e);
}

// B fragments (f16) pre-permuted: idx = ((kt*32 + nt)*64 + l)*8 + i ; nt = g*8 + jt
// row n = g*128 + jt*16 + (l&15) ; k = kt*32 + (l>>4)*8 + i
// W_cat[n][k]: k<64 -> W_ih[n][k], else W_hh[n][k-64].
// ewp[ke][4] = {Wemb[ke][0], Wemb[ke][1], bemb[ke], 0}
__global__ void prep_kernel(const float* __restrict__ Wih, const float* __restrict__ Whh,
                            const float* __restrict__ Wemb, const float* __restrict__ bemb,
                            _Float16* __restrict__ Bp, float* __restrict__ ewp) {
    int t = blockIdx.x * blockDim.x + threadIdx.x;
    if (t < 64) {
        ewp[t * 4 + 0] = Wemb[t * 2 + 0];
        ewp[t * 4 + 1] = Wemb[t * 2 + 1];
        ewp[t * 4 + 2] = bemb[t];
        ewp[t * 4 + 3] = 0.f;
    }
    if (t >= 6 * 32 * 64 * 8) return;
    int i  = t & 7;
    int l  = (t >> 3) & 63;
    int nt = (t >> 9) & 31;
    int kt = t >> 14;
    int n = (nt >> 3) * RNN + (nt & 7) * 16 + (l & 15);
    int k = kt * 32 + ((l >> 4) << 3) + i;
    float val = (k < EMB) ? Wih[n * EMB + k] : Whh[n * RNN + (k - EMB)];
    Bp[t] = (_Float16)val;
}

// Round-7 structure (proven 528us): launch_bounds(512,2) -> 256 VGPR cap, no spill.
// Change vs R7: single-plane f16 A -> 1 MFMA pass (half the MFMA + pack work).
__global__ __launch_bounds__(NT, 2) void lstm_kernel(
    const float* __restrict__ obs,
    const float* __restrict__ ewp,
    const float* __restrict__ bih,  const float* __restrict__ bhh,
    const _Float16* __restrict__ Bp,
    const float* __restrict__ Wout, const float* __restrict__ bout,
    float* __restrict__ out)
{
    // A = [e(64) ; h(128)] single-plane f16, row-major [64 ped][192 k] (384 B rows),
    // XOR-swizzled. B staged per-kt (32 KB slices) double-buffered, per-wave-private.
    __shared__ __align__(16) char smA[64 * 384];    // 24 KB
    __shared__ __align__(16) char smB[2 * 32768];   // 64 KB B dbuf
    __shared__ float part[64 * 2 * 4];
    __shared__ float outs[64 * 2];

    const int tid = threadIdx.x;
    const int l   = tid & 63;
    const int w   = __builtin_amdgcn_readfirstlane(tid >> 6);  // wave 0..7
    const int pg  = blockIdx.x * PB + l;

    // zero A (h region must be 0 at step 0)
    for (int r = tid; r < (64 * 384) / 4; r += NT) ((int*)smA)[r] = 0;

    const int jlane = w * 16 + (l & 15);  // this lane's j column
    const int lrow  = (l >> 4) << 2;      // C/D row base
    const int kgrp  = (l >> 4) << 3;      // A/B k-group base

    float bias[4];
#pragma unroll
    for (int g = 0; g < 4; ++g) {
        int n = g * RNN + jlane;
        bias[g] = bih[n] + bhh[n];
    }

    float c[16];
#pragma unroll
    for (int q = 0; q < 16; ++q) c[q] = 0.f;

    // stage B slice kt into buffer buf: wave w loads its own 4 fragments
    // (nt = g*8+w), each 1 KB, LDS dst = uniform base + lane*16 (linear).
    auto stage = [&](int kt, int buf) {
#pragma unroll
        for (int q = 0; q < 4; ++q) {
            int nt = q * 8 + w;
            const _Float16* src = Bp + (((size_t)kt * 32 + nt) * 64 + l) * 8;
            __builtin_amdgcn_global_load_lds(
                (const __attribute__((address_space(1))) void*)src,
                (__attribute__((address_space(3))) void*)(smB + buf * 32768 + nt * 1024),
                16, 0, 0);
        }
    };

    stage(0, 0);  // prologue: kt0 -> buf0
    __syncthreads();

    for (int step = 0; step < TSTEPS; ++step) {
        // ---- E: e = relu(x @ Wemb.T + bemb) -> A rows k=0..63 (f16)
        float x0, x1;
        if (step < SEQ) {
            const float* xp = obs + ((size_t)step * PEDS + pg) * 2;
            x0 = xp[0]; x1 = xp[1];
        } else {
            x0 = outs[l * 2 + 0];
            x1 = outs[l * 2 + 1];
        }
        {
            half8 vh;
#pragma unroll
            for (int q = 0; q < 8; ++q) {
                const f32x4 ew = *(const f32x4*)(ewp + (w * 8 + q) * 4);
                float v = fmaf(x0, ew[0], fmaf(x1, ew[1], ew[2]));
                v = v > 0.f ? v : 0.f;
                vh[q] = (_Float16)v;
            }
            int off = (l * 384 + w * 16) ^ ((l & 7) << 4);
            *(half8*)(smA + off) = vh;
        }
        __syncthreads();  // B1: e (this step) + h (prev step) visible

        // ---- G: gates = A[64x192] @ B[192x512] + bias ; f16 1-pass, 6 kt phases
        f32x4 acc[4][4];  // [mt][gate]
#pragma unroll
        for (int mt = 0; mt < 4; ++mt)
#pragma unroll
            for (int g = 0; g < 4; ++g) {
                acc[mt][g][0] = bias[g]; acc[mt][g][1] = bias[g];
                acc[mt][g][2] = bias[g]; acc[mt][g][3] = bias[g];
            }
#pragma unroll
        for (int kt = 0; kt < 6; ++kt) {
            const int buf  = kt & 1;
            const int ktn  = (kt < 5) ? kt + 1 : 0;  // kt=5 prefetches next step's kt0
            const int bufn = buf ^ 1;
            stage(ktn, bufn);
            // current buf's 4 loads are the oldest outstanding; allow the 4 just issued
            asm volatile("s_waitcnt vmcnt(4)" ::: "memory");
            half8 bf[4];
#pragma unroll
            for (int g = 0; g < 4; ++g)
                bf[g] = *((const half8*)(smB + buf * 32768 + (g * 8 + w) * 1024) + l);
#pragma unroll
            for (int mt = 0; mt < 4; ++mt) {
                int ped = mt * 16 + (l & 15);
                int off = (ped * 384 + (kt * 32 + kgrp) * 2) ^ ((ped & 7) << 4);
                half8 ah = *(const half8*)(smA + off);
#pragma unroll
                for (int g = 0; g < 4; ++g)
                    acc[mt][g] = __builtin_amdgcn_mfma_f32_16x16x32_f16(ah, bf[g], acc[mt][g], 0, 0, 0);
            }
        }
        __syncthreads();  // B2: all A reads done before h overwrite

        // ---- S: nonlinearities + c/h update; lane owns (ped = mt*16+lrow+r, j = jlane)
#pragma unroll
        for (int mt = 0; mt < 4; ++mt) {
#pragma unroll
            for (int r = 0; r < 4; ++r) {
                float gi = acc[mt][0][r], gf = acc[mt][1][r];
                float gg = acc[mt][2][r], go = acc[mt][3][r];
                float i_ = sigm(gi), f_ = sigm(gf), g_ = tanhfast(gg), o_ = sigm(go);
                float cn = fmaf(f_, c[mt * 4 + r], i_ * g_);
                c[mt * 4 + r] = cn;
                float hn = o_ * tanhfast(cn);
                int ped = mt * 16 + lrow + r;
                int offb = (ped * 384 + 128 + jlane * 2) ^ ((ped & 7) << 4);
                *(_Float16*)(smA + offb) = (_Float16)hn;
            }
        }

        // ---- O: out = h @ Wout.T + bout (h f16 from LDS)
        if (step >= SEQ - 1) {
            __syncthreads();  // B3: h(step) visible
            const int oo = w & 1, jq = w >> 1;
            float s = 0.f;
#pragma unroll
            for (int t = 0; t < 4; ++t) {
                int j = jq * 32 + t * 8;
                int off = (l * 384 + 128 + j * 2) ^ ((l & 7) << 4);
                half8 hh8 = *(const half8*)(smA + off);
                const f32x4 w0 = *(const f32x4*)(Wout + oo * RNN + j);
                const f32x4 w1 = *(const f32x4*)(Wout + oo * RNN + j + 4);
#pragma unroll
                for (int i = 0; i < 4; ++i) {
                    s = fmaf((float)hh8[i], w0[i], s);
                    s = fmaf((float)hh8[i + 4], w1[i], s);
                }
            }
            part[(l * 2 + oo) * 4 + jq] = s;
            __syncthreads();  // B4
            if (tid < 128) {
                int pp = tid & 63, o2 = tid >> 6;
                const float* pr = &part[(pp * 2 + o2) * 4];
                float o = bout[o2] + ((pr[0] + pr[1]) + (pr[2] + pr[3]));
                outs[pp * 2 + o2] = o;
                if (step >= SEQ)
                    out[((size_t)(step - SEQ) * PEDS + (blockIdx.x * PB + pp)) * 2 + o2] = o;
            }
            __syncthreads();  // B5: outs visible for next E
        }
    }
}

extern "C" void kernel_launch(void* const* d_in, const int* in_sizes, int n_in,
                              void* d_out, int out_size, void* d_ws, size_t ws_size,
                              hipStream_t stream) {
    const float* obs  = (const float*)d_in[0];
    const float* Wemb = (const float*)d_in[1];
    const float* bemb = (const float*)d_in[2];
    const float* Wih  = (const float*)d_in[3];
    const float* bih  = (const float*)d_in[4];
    const float* Whh  = (const float*)d_in[5];
    const float* bhh  = (const float*)d_in[6];
    const float* Wout = (const float*)d_in[7];
    const float* bout = (const float*)d_in[8];

    _Float16* Bp  = (_Float16*)d_ws;                 // 98304 f16 = 192 KB
    float*    ewp = (float*)(Bp + 6 * 32 * 64 * 8);  // 64*4 f32 = 1 KB

    prep_kernel<<<(6 * 32 * 64 * 8 + 255) / 256, 256, 0, stream>>>(Wih, Whh, Wemb, bemb, Bp, ewp);
    lstm_kernel<<<PEDS / PB, NT, 0, stream>>>(obs, ewp, bih, bhh, Bp, Wout, bout, (float*)d_out);
}